// Round 1
// 838.945 us; speedup vs baseline: 1.0442x; 1.0442x over previous
//
#include <hip/hip_runtime.h>

#define N_PTS 500000
#define C_CLUST 40000
#define NGC (2 * C_CLUST)
#define CAP 64            // bucket capacity per (group,cluster); Poisson(8.1) => P(>64) ~ 0
#define KX 192            // padded D_IN: [0..90]=raw, [91..95]=0, [96..186]=cluster means, [187..191]=0
#define EPS 1e-5f
#define SLOPE 0.1f
#define NREP 64           // BN-stat atomic replicas (spread 2M RMWs over 64x more lines)

typedef __attribute__((ext_vector_type(8))) short short8;
typedef __attribute__((ext_vector_type(4))) float floatx4;

// ---- workspace layout (bytes) ----
#define OFF_CURS     0ULL                              // 80000 i32 = 320,000
#define OFF_COLSUM   320000ULL                         // 64 replicas x 128 f32 = 32,768
#define OFF_COLSUMSQ 352768ULL                         // 64 replicas x 128 f32 = 32,768
#define OFF_BNPAR    385536ULL                         // 128 float2 = 1,024
#define OFF_BUCKETS  386560ULL                         // 80000*64*4 = 20,480,000
#define OFF_MEANS    (OFF_BUCKETS + 20480000ULL)       // 80000*96 bf16 = 15,360,000
#define OFF_WBF      (OFF_MEANS + 15360000ULL)         // 128*192 bf16 = 49,152
#define MEMSET_BYTES 385536ULL                         // cursors + colsum + colsumsq
// total ~36.3 MB of d_ws

static __device__ __forceinline__ unsigned short f32_to_bf16(float v) {
    unsigned int u = __float_as_uint(v);
    u += 0x7fffu + ((u >> 16) & 1u);   // RNE
    return (unsigned short)(u >> 16);
}

// K1: bucket points by (group, cluster). 500k cheap atomics on a 320KB cursor array.
__global__ void bucket_kernel(const int* __restrict__ idx, const int* __restrict__ mask,
                              int* __restrict__ curs, int* __restrict__ buckets) {
    int t = blockIdx.x * 256 + threadIdx.x;
    if (t >= N_PTS) return;
    int gc = (mask[t] ? 0 : 1) * C_CLUST + idx[t];
    int pos = atomicAdd(&curs[gc], 1);
    if (pos < CAP) buckets[gc * CAP + pos] = t;
}

// K2: one wave per (group,cluster): gather its points, mean, write bf16 means row [96].
__global__ __launch_bounds__(256) void means_kernel(
        const float* __restrict__ feat, const float* __restrict__ logits,
        const float* __restrict__ pts, const float* __restrict__ proj,
        const int* __restrict__ curs, const int* __restrict__ buckets,
        unsigned short* __restrict__ means) {
    int wv = (blockIdx.x * 256 + threadIdx.x) >> 6;
    int lane = threadIdx.x & 63;
    if (wv >= NGC) return;
    int cnt = curs[wv];
    if (cnt > CAP) cnt = CAP;
    int plist = (lane < cnt) ? buckets[wv * CAP + lane] : 0;
    float accf = 0.f, acce = 0.f;
    for (int i = 0; i < cnt; ++i) {
        int p = __shfl(plist, i);
        accf += feat[(size_t)p * 64 + lane];
        if (lane < 27) {
            float v;
            if (lane < 20)      v = logits[(size_t)p * 20 + lane];
            else if (lane < 24) v = pts[(size_t)p * 4 + (lane - 20)];
            else                v = proj[(size_t)p * 3 + (lane - 24)];
            acce += v;
        }
    }
    float rc = (cnt > 0) ? (1.f / (float)cnt) : 0.f;
    unsigned short* row = means + (size_t)wv * 96;
    row[lane] = f32_to_bf16(accf * rc);                         // cols 0..63 (feat)
    if (lane < 32)                                              // cols 64..95
        row[64 + lane] = (lane < 27) ? f32_to_bf16(acce * rc) : (unsigned short)0;
}

// K3: W (128x182 f32) -> column-permuted bf16 (128x192)
__global__ void wconv_kernel(const float* __restrict__ W, unsigned short* __restrict__ wbf) {
    int t = blockIdx.x * 256 + threadIdx.x;
    if (t >= 128 * KX) return;
    int k = t % KX;
    int j = t / KX;
    float v = 0.f;
    if (k < 91)                  v = W[j * 182 + k];
    else if (k >= 96 && k < 187) v = W[j * 182 + (k - 5)];
    wbf[t] = f32_to_bf16(v);
}

// K4: fused x-construction + bf16 MFMA GEMM + bias + BN stat partials.
// Block: 64 points x 128 outputs, K=192 in LDS (XOR-swizzled). 25.6KB LDS -> 6 blocks/CU.
__global__ __launch_bounds__(256, 6) void gemm_kernel(
    const float* __restrict__ feat, const float* __restrict__ logits,
    const float* __restrict__ pts, const float* __restrict__ proj,
    const int* __restrict__ idx, const int* __restrict__ mask,
    const unsigned short* __restrict__ means, const unsigned short* __restrict__ wbf,
    const float* __restrict__ bias,
    float* __restrict__ hout, float* __restrict__ colsum, float* __restrict__ colsumsq)
{
    __shared__ unsigned short xs[64 * KX];
    __shared__ float bns[256];
    int tid = threadIdx.x;
    bns[tid] = 0.f;
    int nbase = blockIdx.x * 64;

    // stage raw features (cols 0..95) as bf16 into swizzled LDS
    for (int e = tid; e < 64 * 96; e += 256) {
        int row = e / 96;
        int col = e - row * 96;
        int n = nbase + row;
        float v = 0.f;
        if (n < N_PTS) {
            if (col < 64)      v = feat[(size_t)n * 64 + col];
            else if (col < 84) v = logits[(size_t)n * 20 + (col - 64)];
            else if (col < 88) v = pts[(size_t)n * 4 + (col - 84)];
            else if (col < 91) v = proj[(size_t)n * 3 + (col - 88)];
        }
        int qc = col >> 3;
        int phys = ((qc ^ (row & 7)) << 3) | (col & 7);
        xs[row * KX + phys] = f32_to_bf16(v);
    }
    // stage cluster means (cols 96..191): 4 threads per row, 3 uint4 (48B) each
    {
        int row = tid >> 2, q4 = tid & 3;
        int n = nbase + row;
        uint4 d[3];
        if (n < N_PTS) {
            int gc = (mask[n] ? 0 : 1) * C_CLUST + idx[n];
            const uint4* src = reinterpret_cast<const uint4*>(means + (size_t)gc * 96 + q4 * 24);
            d[0] = src[0]; d[1] = src[1]; d[2] = src[2];
        } else {
            d[0] = d[1] = d[2] = make_uint4(0, 0, 0, 0);
        }
        #pragma unroll
        for (int i = 0; i < 3; ++i) {
            int qc = 12 + q4 * 3 + i;
            int phys = qc ^ (row & 7);
            *reinterpret_cast<uint4*>(&xs[row * KX + (phys << 3)]) = d[i];
        }
    }
    __syncthreads();

    int wave = tid >> 6, lane = tid & 63;
    int mbase = (wave & 1) * 32;       // point-rows for this wave
    int jbase = (wave >> 1) * 64;      // output-cols for this wave
    int lrow = lane & 15, q = lane >> 4;

    floatx4 acc[2][4];
    #pragma unroll
    for (int a = 0; a < 2; ++a)
        #pragma unroll
        for (int b = 0; b < 4; ++b) { floatx4 z = {0.f, 0.f, 0.f, 0.f}; acc[a][b] = z; }

    #pragma unroll 1
    for (int ks = 0; ks < 6; ++ks) {
        int kb = ks * 32;
        short8 af[2], bfr[4];
        #pragma unroll
        for (int it = 0; it < 2; ++it) {
            int row = mbase + it * 16 + lrow;          // A: m = lane&15
            int qc = (kb >> 3) + q;                    // k = q*8 + j
            int phys = qc ^ (row & 7);
            af[it] = *reinterpret_cast<const short8*>(&xs[row * KX + (phys << 3)]);
        }
        #pragma unroll
        for (int jt = 0; jt < 4; ++jt) {
            int j = jbase + jt * 16 + lrow;            // B: n = lane&15, k = q*8 + j
            bfr[jt] = *reinterpret_cast<const short8*>(wbf + (size_t)j * KX + kb + q * 8);
        }
        #pragma unroll
        for (int it = 0; it < 2; ++it)
            #pragma unroll
            for (int jt = 0; jt < 4; ++jt)
                acc[it][jt] = __builtin_amdgcn_mfma_f32_16x16x32_bf16(af[it], bfr[jt], acc[it][jt], 0, 0, 0);
    }

    // epilogue: bias, store h, column sum/sumsq partials
    // C/D layout: col = lane&15, row = q*4 + reg  [m89/m91-verified]
    #pragma unroll
    for (int jt = 0; jt < 4; ++jt) {
        int j = jbase + jt * 16 + lrow;
        float bj = bias[j];
        float s = 0.f, s2 = 0.f;
        #pragma unroll
        for (int it = 0; it < 2; ++it) {
            #pragma unroll
            for (int r = 0; r < 4; ++r) {
                int n = nbase + mbase + it * 16 + q * 4 + r;
                if (n < N_PTS) {
                    float v = acc[it][jt][r] + bj;
                    hout[(size_t)n * 128 + j] = v;
                    s += v; s2 += v * v;
                }
            }
        }
        s  += __shfl_xor(s, 16);  s  += __shfl_xor(s, 32);
        s2 += __shfl_xor(s2, 16); s2 += __shfl_xor(s2, 32);
        if (q == 0) {
            atomicAdd(&bns[j], s);
            atomicAdd(&bns[128 + j], s2);
        }
    }
    __syncthreads();
    // spread the 2M device-scope BN-stat RMWs over 64 replicas to kill
    // coherence-point line contention (was: all blocks -> same 8 lines)
    if (tid < 128) {
        int rep = (blockIdx.x & (NREP - 1)) << 7;
        atomicAdd(&colsum[rep + tid], bns[tid]);
        atomicAdd(&colsumsq[rep + tid], bns[128 + tid]);
    }
}

// K5: BN affine params from global stats (reduce the 64 replicas first)
__global__ void bnpar_kernel(const float* __restrict__ colsum, const float* __restrict__ colsumsq,
                             const float* __restrict__ gamma, const float* __restrict__ beta,
                             float2* __restrict__ bnpar) {
    int j = threadIdx.x;
    if (j < 128) {
        float s = 0.f, s2 = 0.f;
        #pragma unroll 4
        for (int r = 0; r < NREP; ++r) {
            s  += colsum[r * 128 + j];      // coalesced across j
            s2 += colsumsq[r * 128 + j];
        }
        float invN = 1.0f / (float)N_PTS;
        float mu = s * invN;
        float var = s2 * invN - mu * mu;
        float rstd = rsqrtf(var + EPS);
        float sc = gamma[j] * rstd;
        float sh = beta[j] - mu * sc;
        bnpar[j] = make_float2(sc, sh);
    }
}

// K6: in-place normalize + LeakyReLU over d_out
__global__ void norm_kernel(float* __restrict__ hout, const float2* __restrict__ bnpar) {
    size_t t = (size_t)blockIdx.x * blockDim.x + threadIdx.x;
    size_t e = t * 4;
    if (e >= (size_t)N_PTS * 128) return;
    float4 v = *reinterpret_cast<float4*>(hout + e);
    int j0 = (int)(e & 127);
    float2 p0 = bnpar[j0], p1 = bnpar[j0 + 1], p2 = bnpar[j0 + 2], p3 = bnpar[j0 + 3];
    v.x = v.x * p0.x + p0.y;
    v.y = v.y * p1.x + p1.y;
    v.z = v.z * p2.x + p2.y;
    v.w = v.w * p3.x + p3.y;
    v.x = v.x >= 0.f ? v.x : SLOPE * v.x;
    v.y = v.y >= 0.f ? v.y : SLOPE * v.y;
    v.z = v.z >= 0.f ? v.z : SLOPE * v.z;
    v.w = v.w >= 0.f ? v.w : SLOPE * v.w;
    *reinterpret_cast<float4*>(hout + e) = v;
}

extern "C" void kernel_launch(void* const* d_in, const int* in_sizes, int n_in,
                              void* d_out, int out_size, void* d_ws, size_t ws_size,
                              hipStream_t stream) {
    const float* pts    = (const float*)d_in[0];
    const float* proj   = (const float*)d_in[1];
    const float* feat   = (const float*)d_in[2];
    const float* logits = (const float*)d_in[3];
    const int*   idx    = (const int*)d_in[4];
    const int*   mask   = (const int*)d_in[5];
    const float* W      = (const float*)d_in[6];
    const float* bias   = (const float*)d_in[7];
    const float* gamma  = (const float*)d_in[8];
    const float* beta   = (const float*)d_in[9];

    char* ws = (char*)d_ws;
    int*            curs     = (int*)(ws + OFF_CURS);
    float*          colsum   = (float*)(ws + OFF_COLSUM);
    float*          colsumsq = (float*)(ws + OFF_COLSUMSQ);
    float2*         bnpar    = (float2*)(ws + OFF_BNPAR);
    int*            buckets  = (int*)(ws + OFF_BUCKETS);
    unsigned short* means    = (unsigned short*)(ws + OFF_MEANS);
    unsigned short* wbf      = (unsigned short*)(ws + OFF_WBF);
    float*          hout     = (float*)d_out;

    hipMemsetAsync(ws, 0, MEMSET_BYTES, stream);   // cursors + colsum/colsumsq replicas

    bucket_kernel<<<(N_PTS + 255) / 256, 256, 0, stream>>>(idx, mask, curs, buckets);
    means_kernel<<<NGC / 4, 256, 0, stream>>>(feat, logits, pts, proj, curs, buckets, means);
    wconv_kernel<<<(128 * KX) / 256, 256, 0, stream>>>(W, wbf);
    gemm_kernel<<<(N_PTS + 63) / 64, 256, 0, stream>>>(feat, logits, pts, proj, idx, mask,
                                                       means, wbf, bias, hout, colsum, colsumsq);
    bnpar_kernel<<<1, 128, 0, stream>>>(colsum, colsumsq, gamma, beta, bnpar);
    norm_kernel<<<((size_t)N_PTS * 128 / 4 + 255) / 256, 256, 0, stream>>>(hout, bnpar);
}

// Round 2
// 691.341 us; speedup vs baseline: 1.2671x; 1.2135x over previous
//
#include <hip/hip_runtime.h>

#define N_PTS 500000
#define C_CLUST 40000
#define NGC (2 * C_CLUST)
#define CAP 64            // bucket capacity per (group,cluster); Poisson(8.1) => P(>64) ~ 0
#define KX 192            // padded D_IN: [0..90]=raw, [91..95]=0, [96..186]=cluster means, [187..191]=0
#define EPS 1e-5f
#define SLOPE 0.1f
#define NREP 64           // BN-stat atomic replicas (spread 2M RMWs over 64x more lines)

typedef __attribute__((ext_vector_type(8))) short short8;
typedef __attribute__((ext_vector_type(4))) float floatx4;

// ---- workspace layout (bytes) ----
#define OFF_CURS     0ULL                              // 80000 i32 = 320,000
#define OFF_COLSUM   320000ULL                         // 64 replicas x 128 f32 = 32,768
#define OFF_COLSUMSQ 352768ULL                         // 64 replicas x 128 f32 = 32,768
#define OFF_BNPAR    385536ULL                         // 128 float2 = 1,024
#define OFF_BUCKETS  386560ULL                         // 80000*64*4 = 20,480,000
#define OFF_MEANS    (OFF_BUCKETS + 20480000ULL)       // 80000*96 bf16 = 15,360,000
#define OFF_WBF      (OFF_MEANS + 15360000ULL)         // 128*192 bf16 = 49,152
#define MEMSET_BYTES 385536ULL                         // cursors + colsum + colsumsq
// total ~36.3 MB of d_ws

static __device__ __forceinline__ unsigned short f32_to_bf16(float v) {
    unsigned int u = __float_as_uint(v);
    u += 0x7fffu + ((u >> 16) & 1u);   // RNE
    return (unsigned short)(u >> 16);
}

static __device__ __forceinline__ short8 cvt8(float4 a, float4 b) {
    short8 r;
    r[0] = (short)f32_to_bf16(a.x); r[1] = (short)f32_to_bf16(a.y);
    r[2] = (short)f32_to_bf16(a.z); r[3] = (short)f32_to_bf16(a.w);
    r[4] = (short)f32_to_bf16(b.x); r[5] = (short)f32_to_bf16(b.y);
    r[6] = (short)f32_to_bf16(b.z); r[7] = (short)f32_to_bf16(b.w);
    return r;
}

// K1: bucket points by (group, cluster). 500k cheap atomics on a 320KB cursor array.
__global__ void bucket_kernel(const int* __restrict__ idx, const int* __restrict__ mask,
                              int* __restrict__ curs, int* __restrict__ buckets) {
    int t = blockIdx.x * 256 + threadIdx.x;
    if (t >= N_PTS) return;
    int gc = (mask[t] ? 0 : 1) * C_CLUST + idx[t];
    int pos = atomicAdd(&curs[gc], 1);
    if (pos < CAP) buckets[gc * CAP + pos] = t;
}

static __device__ __forceinline__ float small_feat(const float* __restrict__ logits,
                                                   const float* __restrict__ pts,
                                                   const float* __restrict__ proj,
                                                   int p, int lane) {
    if (lane < 20)      return logits[(size_t)p * 20 + lane];
    else if (lane < 24) return pts[(size_t)p * 4 + (lane - 20)];
    else                return proj[(size_t)p * 3 + (lane - 24)];
}

// K2: one wave per (group,cluster): gather its points, mean, write bf16 means row [96].
// 4-way ILP unroll: 4 independent gather chains in flight instead of 1.
__global__ __launch_bounds__(256) void means_kernel(
        const float* __restrict__ feat, const float* __restrict__ logits,
        const float* __restrict__ pts, const float* __restrict__ proj,
        const int* __restrict__ curs, const int* __restrict__ buckets,
        unsigned short* __restrict__ means) {
    int wv = (blockIdx.x * 256 + threadIdx.x) >> 6;
    int lane = threadIdx.x & 63;
    if (wv >= NGC) return;
    int cnt = curs[wv];
    if (cnt > CAP) cnt = CAP;
    int plist = (lane < cnt) ? buckets[wv * CAP + lane] : 0;
    float a0 = 0.f, a1 = 0.f, a2 = 0.f, a3 = 0.f;
    float e0 = 0.f, e1 = 0.f, e2 = 0.f, e3 = 0.f;
    bool sm = (lane < 27);
    int i = 0;
    for (; i + 4 <= cnt; i += 4) {
        int p0 = __shfl(plist, i), p1 = __shfl(plist, i + 1);
        int p2 = __shfl(plist, i + 2), p3 = __shfl(plist, i + 3);
        a0 += feat[(size_t)p0 * 64 + lane];
        a1 += feat[(size_t)p1 * 64 + lane];
        a2 += feat[(size_t)p2 * 64 + lane];
        a3 += feat[(size_t)p3 * 64 + lane];
        if (sm) {
            e0 += small_feat(logits, pts, proj, p0, lane);
            e1 += small_feat(logits, pts, proj, p1, lane);
            e2 += small_feat(logits, pts, proj, p2, lane);
            e3 += small_feat(logits, pts, proj, p3, lane);
        }
    }
    for (; i < cnt; ++i) {
        int p = __shfl(plist, i);
        a0 += feat[(size_t)p * 64 + lane];
        if (sm) e0 += small_feat(logits, pts, proj, p, lane);
    }
    float accf = (a0 + a1) + (a2 + a3);
    float acce = (e0 + e1) + (e2 + e3);
    float rc = (cnt > 0) ? (1.f / (float)cnt) : 0.f;
    unsigned short* row = means + (size_t)wv * 96;
    row[lane] = f32_to_bf16(accf * rc);                         // cols 0..63 (feat)
    if (lane < 32)                                              // cols 64..95
        row[64 + lane] = (lane < 27) ? f32_to_bf16(acce * rc) : (unsigned short)0;
}

// K3: W (128x182 f32) -> column-permuted bf16 (128x192)
__global__ void wconv_kernel(const float* __restrict__ W, unsigned short* __restrict__ wbf) {
    int t = blockIdx.x * 256 + threadIdx.x;
    if (t >= 128 * KX) return;
    int k = t % KX;
    int j = t / KX;
    float v = 0.f;
    if (k < 91)                  v = W[j * 182 + k];
    else if (k >= 96 && k < 187) v = W[j * 182 + (k - 5)];
    wbf[t] = f32_to_bf16(v);
}

// K4: fused x-construction + bf16 MFMA GEMM + bias + BN stat partials.
// Block: 64 points x 128 outputs, K=192 in LDS (XOR-swizzled). 25.6KB LDS -> 6 blocks/CU.
// Staging: fully vectorized. Thread (row=tid>>2, sub=tid&3) owns 3 raw quads (8 bf16 each)
// loaded as float4 pairs + 3 means uint4s. Means gather issued FIRST (longest latency).
__global__ __launch_bounds__(256, 6) void gemm_kernel(
    const float* __restrict__ feat, const float* __restrict__ logits,
    const float* __restrict__ pts, const float* __restrict__ proj,
    const int* __restrict__ idx, const int* __restrict__ mask,
    const unsigned short* __restrict__ means, const unsigned short* __restrict__ wbf,
    const float* __restrict__ bias,
    float* __restrict__ hout, float* __restrict__ colsum, float* __restrict__ colsumsq)
{
    __shared__ unsigned short xs[64 * KX];
    __shared__ float bns[256];
    int tid = threadIdx.x;
    bns[tid] = 0.f;
    int nbase = blockIdx.x * 64;

    int row = tid >> 2, sub = tid & 3;
    int n = nbase + row;
    bool ok = (n < N_PTS);

    // --- issue the random means gather first: its L2/L3 latency hides under raw loads ---
    uint4 d[3];
    if (ok) {
        int gc = (mask[n] ? 0 : 1) * C_CLUST + idx[n];
        const uint4* src = reinterpret_cast<const uint4*>(means + (size_t)gc * 96 + sub * 24);
        d[0] = src[0]; d[1] = src[1]; d[2] = src[2];
    } else {
        d[0] = d[1] = d[2] = make_uint4(0, 0, 0, 0);
    }

    // --- raw features: 3 quads (= 6 float4 loads) per thread, all independent ---
    float4 va[6];
    if (ok) {
        if (sub < 2) {                 // quads 0..5: feat[0..47]
            const float4* f4 = reinterpret_cast<const float4*>(feat + (size_t)n * 64) + sub * 6;
            #pragma unroll
            for (int i = 0; i < 6; ++i) va[i] = f4[i];
        } else if (sub == 2) {         // quads 6,7: feat[48..63]; quad 8: logits[0..7]
            const float4* f4 = reinterpret_cast<const float4*>(feat + (size_t)n * 64) + 12;
            va[0] = f4[0]; va[1] = f4[1]; va[2] = f4[2]; va[3] = f4[3];
            const float4* l4 = reinterpret_cast<const float4*>(logits + (size_t)n * 20);
            va[4] = l4[0]; va[5] = l4[1];
        } else {                       // quad 9: logits[8..15]; quad 10: logits[16..19]+pts; quad 11: proj+0
            const float4* l4 = reinterpret_cast<const float4*>(logits + (size_t)n * 20);
            va[0] = l4[2]; va[1] = l4[3];
            va[2] = l4[4];
            va[3] = *reinterpret_cast<const float4*>(pts + (size_t)n * 4);
            const float* pr = proj + (size_t)n * 3;
            va[4] = make_float4(pr[0], pr[1], pr[2], 0.f);
            va[5] = make_float4(0.f, 0.f, 0.f, 0.f);
        }
    } else {
        #pragma unroll
        for (int i = 0; i < 6; ++i) va[i] = make_float4(0.f, 0.f, 0.f, 0.f);
    }
    #pragma unroll
    for (int t = 0; t < 3; ++t) {
        int qc = 3 * sub + t;
        int phys = qc ^ (row & 7);
        *reinterpret_cast<short8*>(&xs[row * KX + (phys << 3)]) = cvt8(va[2 * t], va[2 * t + 1]);
    }
    // --- means quads 12..23 ---
    #pragma unroll
    for (int i = 0; i < 3; ++i) {
        int qc = 12 + sub * 3 + i;
        int phys = qc ^ (row & 7);
        *reinterpret_cast<uint4*>(&xs[row * KX + (phys << 3)]) = d[i];
    }
    __syncthreads();

    int wave = tid >> 6, lane = tid & 63;
    int mbase = (wave & 1) * 32;       // point-rows for this wave
    int jbase = (wave >> 1) * 64;      // output-cols for this wave
    int lrow = lane & 15, q = lane >> 4;

    floatx4 acc[2][4];
    #pragma unroll
    for (int a = 0; a < 2; ++a)
        #pragma unroll
        for (int b = 0; b < 4; ++b) { floatx4 z = {0.f, 0.f, 0.f, 0.f}; acc[a][b] = z; }

    #pragma unroll 1
    for (int ks = 0; ks < 6; ++ks) {
        int kb = ks * 32;
        short8 af[2], bfr[4];
        #pragma unroll
        for (int it = 0; it < 2; ++it) {
            int r2 = mbase + it * 16 + lrow;           // A: m = lane&15
            int qc = (kb >> 3) + q;                    // k = q*8 + j
            int phys = qc ^ (r2 & 7);
            af[it] = *reinterpret_cast<const short8*>(&xs[r2 * KX + (phys << 3)]);
        }
        #pragma unroll
        for (int jt = 0; jt < 4; ++jt) {
            int j = jbase + jt * 16 + lrow;            // B: n = lane&15, k = q*8 + j
            bfr[jt] = *reinterpret_cast<const short8*>(wbf + (size_t)j * KX + kb + q * 8);
        }
        #pragma unroll
        for (int it = 0; it < 2; ++it)
            #pragma unroll
            for (int jt = 0; jt < 4; ++jt)
                acc[it][jt] = __builtin_amdgcn_mfma_f32_16x16x32_bf16(af[it], bfr[jt], acc[it][jt], 0, 0, 0);
    }

    // epilogue: bias, store h, column sum/sumsq partials
    // C/D layout: col = lane&15, row = q*4 + reg  [m89/m91-verified]
    #pragma unroll
    for (int jt = 0; jt < 4; ++jt) {
        int j = jbase + jt * 16 + lrow;
        float bj = bias[j];
        float s = 0.f, s2 = 0.f;
        #pragma unroll
        for (int it = 0; it < 2; ++it) {
            #pragma unroll
            for (int r = 0; r < 4; ++r) {
                int nn = nbase + mbase + it * 16 + q * 4 + r;
                if (nn < N_PTS) {
                    float v = acc[it][jt][r] + bj;
                    hout[(size_t)nn * 128 + j] = v;
                    s += v; s2 += v * v;
                }
            }
        }
        s  += __shfl_xor(s, 16);  s  += __shfl_xor(s, 32);
        s2 += __shfl_xor(s2, 16); s2 += __shfl_xor(s2, 32);
        if (q == 0) {
            atomicAdd(&bns[j], s);
            atomicAdd(&bns[128 + j], s2);
        }
    }
    __syncthreads();
    // spread the 2M device-scope BN-stat RMWs over 64 replicas to kill
    // coherence-point line contention (was: all blocks -> same 8 lines)
    if (tid < 128) {
        int rep = (blockIdx.x & (NREP - 1)) << 7;
        atomicAdd(&colsum[rep + tid], bns[tid]);
        atomicAdd(&colsumsq[rep + tid], bns[128 + tid]);
    }
}

// K5: BN affine params from global stats (reduce the 64 replicas first)
__global__ void bnpar_kernel(const float* __restrict__ colsum, const float* __restrict__ colsumsq,
                             const float* __restrict__ gamma, const float* __restrict__ beta,
                             float2* __restrict__ bnpar) {
    int j = threadIdx.x;
    if (j < 128) {
        float s = 0.f, s2 = 0.f;
        #pragma unroll 4
        for (int r = 0; r < NREP; ++r) {
            s  += colsum[r * 128 + j];      // coalesced across j
            s2 += colsumsq[r * 128 + j];
        }
        float invN = 1.0f / (float)N_PTS;
        float mu = s * invN;
        float var = s2 * invN - mu * mu;
        float rstd = rsqrtf(var + EPS);
        float sc = gamma[j] * rstd;
        float sh = beta[j] - mu * sc;
        bnpar[j] = make_float2(sc, sh);
    }
}

// K6: in-place normalize + LeakyReLU over d_out
__global__ void norm_kernel(float* __restrict__ hout, const float2* __restrict__ bnpar) {
    size_t t = (size_t)blockIdx.x * blockDim.x + threadIdx.x;
    size_t e = t * 4;
    if (e >= (size_t)N_PTS * 128) return;
    float4 v = *reinterpret_cast<float4*>(hout + e);
    int j0 = (int)(e & 127);
    float2 p0 = bnpar[j0], p1 = bnpar[j0 + 1], p2 = bnpar[j0 + 2], p3 = bnpar[j0 + 3];
    v.x = v.x * p0.x + p0.y;
    v.y = v.y * p1.x + p1.y;
    v.z = v.z * p2.x + p2.y;
    v.w = v.w * p3.x + p3.y;
    v.x = v.x >= 0.f ? v.x : SLOPE * v.x;
    v.y = v.y >= 0.f ? v.y : SLOPE * v.y;
    v.z = v.z >= 0.f ? v.z : SLOPE * v.z;
    v.w = v.w >= 0.f ? v.w : SLOPE * v.w;
    *reinterpret_cast<float4*>(hout + e) = v;
}

extern "C" void kernel_launch(void* const* d_in, const int* in_sizes, int n_in,
                              void* d_out, int out_size, void* d_ws, size_t ws_size,
                              hipStream_t stream) {
    const float* pts    = (const float*)d_in[0];
    const float* proj   = (const float*)d_in[1];
    const float* feat   = (const float*)d_in[2];
    const float* logits = (const float*)d_in[3];
    const int*   idx    = (const int*)d_in[4];
    const int*   mask   = (const int*)d_in[5];
    const float* W      = (const float*)d_in[6];
    const float* bias   = (const float*)d_in[7];
    const float* gamma  = (const float*)d_in[8];
    const float* beta   = (const float*)d_in[9];

    char* ws = (char*)d_ws;
    int*            curs     = (int*)(ws + OFF_CURS);
    float*          colsum   = (float*)(ws + OFF_COLSUM);
    float*          colsumsq = (float*)(ws + OFF_COLSUMSQ);
    float2*         bnpar    = (float2*)(ws + OFF_BNPAR);
    int*            buckets  = (int*)(ws + OFF_BUCKETS);
    unsigned short* means    = (unsigned short*)(ws + OFF_MEANS);
    unsigned short* wbf      = (unsigned short*)(ws + OFF_WBF);
    float*          hout     = (float*)d_out;

    hipMemsetAsync(ws, 0, MEMSET_BYTES, stream);   // cursors + colsum/colsumsq replicas

    bucket_kernel<<<(N_PTS + 255) / 256, 256, 0, stream>>>(idx, mask, curs, buckets);
    means_kernel<<<NGC / 4, 256, 0, stream>>>(feat, logits, pts, proj, curs, buckets, means);
    wconv_kernel<<<(128 * KX) / 256, 256, 0, stream>>>(W, wbf);
    gemm_kernel<<<(N_PTS + 63) / 64, 256, 0, stream>>>(feat, logits, pts, proj, idx, mask,
                                                       means, wbf, bias, hout, colsum, colsumsq);
    bnpar_kernel<<<1, 128, 0, stream>>>(colsum, colsumsq, gamma, beta, bnpar);
    norm_kernel<<<((size_t)N_PTS * 128 / 4 + 255) / 256, 256, 0, stream>>>(hout, bnpar);
}